// Round 6
// baseline (200.822 us; speedup 1.0000x reference)
//
#include <hip/hip_runtime.h>

// Problem constants: B=64, I=512, H=1024, D=I+H=1536
constexpr int Bn = 64;
constexpr int In = 512;
constexpr int Hn = 1024;
constexpr int Dn = 1536;
constexpr float ALPHA = 0.001f;
constexpr int RPW = 8;                 // rows per wave
constexpr int LDS_FLOATS = 6144 + 4 * 2 * 3072;   // W (24KB) + 4 waves x 2 slots x 12KB = 120 KB

typedef float nfloat4 __attribute__((ext_vector_type(4)));

// Async global->LDS DMA, 16 B per lane (global_load_lds_dwordx4).
// Global src is per-lane; LDS dst is wave-uniform base (+ lane*16 by HW).
__device__ __forceinline__ void dma16(const float* g, float* l) {
    __builtin_amdgcn_global_load_lds(
        (const __attribute__((address_space(1))) void*)g,
        (__attribute__((address_space(3))) void*)l, 16, 0, 0);
}

// Block = (k, 32 b): 2048 blocks, 4 waves, 8 rows/wave.
// All row data (wih 6KB + x 6KB) is DMA'd into wave-private LDS ring slots:
// in-flight bytes live in LDS, not VGPRs (R5 lesson: register prefetch and
// occupancy are incompatible; fill kernel saturates HBM at 10% occupancy).
// Barrier-free main loop with hand-counted vmcnt (in-order retirement):
//   per row: [wait vmcnt][12x ds_read_b128 -> regs][dot/shfl/tanh]
//            [7 stores][12x global_load_lds for row r+2]
// Steady-state wait = vmcnt(19): leaves st(r-1) 7 + DMA(r+1) 12 outstanding.
__global__ __launch_bounds__(256) void prnn_fused_kernel(
    const float* __restrict__ inputs,   // B x I
    const float* __restrict__ hidden,   // B x H
    const float* __restrict__ wih,      // B x H x D
    const float* __restrict__ Wa,       // H x D
    const float* __restrict__ Wb,       // H x D
    const float* __restrict__ Wc,       // H x D
    const float* __restrict__ Wd,       // H x D
    const float* __restrict__ bih,      // H
    float* __restrict__ out_hidden,     // B x H
    float* __restrict__ out_wih)        // B x H x D
{
    extern __shared__ float lds[];      // [0,6144): W as 4x384 float4; slots after

    const int k     = blockIdx.x >> 1;
    const int bbase = (blockIdx.x & 1) * 32;
    const int tid   = threadIdx.x;
    const int wv    = tid >> 6;
    const int lane  = tid & 63;

    // Cooperative LDS stage of Wa..Wd row k (384 float4 per tensor).
    {
        float4* s4 = (float4*)lds;
        const float4* wa4 = (const float4*)(Wa + (size_t)k * Dn);
        const float4* wb4 = (const float4*)(Wb + (size_t)k * Dn);
        const float4* wc4 = (const float4*)(Wc + (size_t)k * Dn);
        const float4* wd4 = (const float4*)(Wd + (size_t)k * Dn);
        #pragma unroll
        for (int e = 0; e < 2; ++e) {
            const int i = tid + e * 256;
            if (i < 384) {
                s4[i]        = wa4[i];
                s4[384 + i]  = wb4[i];
                s4[768 + i]  = wc4[i];
                s4[1152 + i] = wd4[i];
            }
        }
    }
    __syncthreads();   // drains stage loads: vmcnt known-zero at loop entry

    const int b0   = bbase + wv * RPW;
    const float bk = bih[k];
    float* const slot0 = &lds[6144 + (wv * 2 + 0) * 3072];
    float* const slot1 = &lds[6144 + (wv * 2 + 1) * 3072];

    // 12 DMA instructions per row: wih (6 KB) then x = inputs|hidden (6 KB).
    auto dma_row = [&](int r, float* slot) {
        const int b = b0 + r;
        const float* __restrict__ wrow = wih + ((size_t)b * Hn + k) * Dn;
        #pragma unroll
        for (int c = 0; c < 6; ++c) dma16(wrow + c * 256 + lane * 4, slot + c * 256);
        const float* __restrict__ xin = inputs + b * In;
        #pragma unroll
        for (int c = 0; c < 2; ++c) dma16(xin + c * 256 + lane * 4, slot + 1536 + c * 256);
        const float* __restrict__ xh = hidden + b * Hn;
        #pragma unroll
        for (int c = 0; c < 4; ++c) dma16(xh + c * 256 + lane * 4, slot + 2048 + c * 256);
    };

    // Prologue: 2 rows (24 loads) in flight.
    dma_row(0, slot0);
    dma_row(1, slot1);

    #pragma unroll
    for (int r = 0; r < RPW; ++r) {     // fully unrolled: r is compile-time
        // Hand-counted wait for DMA(r); leaves newer ops in flight.
        //   r=0:     outstanding D0(12)+D1(12)          -> vmcnt(12)
        //   steady:  st(r-2)(7)+D(r)(12)+st(r-1)(7)+D(r+1)(12) -> vmcnt(19)
        //   r=RPW-1: st(r-2)(7)+D(r)(12)+st(r-1)(7)     -> vmcnt(7)
        __builtin_amdgcn_sched_barrier(0);
        if (r == 0)            asm volatile("s_waitcnt vmcnt(12)" ::: "memory");
        else if (r == RPW - 1) asm volatile("s_waitcnt vmcnt(7)"  ::: "memory");
        else                   asm volatile("s_waitcnt vmcnt(19)" ::: "memory");
        __builtin_amdgcn_sched_barrier(0);

        const float* slot = (r & 1) ? slot1 : slot0;
        float4 w[6], x[6];
        #pragma unroll
        for (int c = 0; c < 6; ++c)
            w[c] = *(const float4*)(slot + c * 256 + lane * 4);
        #pragma unroll
        for (int c = 0; c < 6; ++c)
            x[c] = *(const float4*)(slot + 1536 + c * 256 + lane * 4);

        float acc = 0.0f;
        #pragma unroll
        for (int c = 0; c < 6; ++c)
            acc += w[c].x * x[c].x + w[c].y * x[c].y
                 + w[c].z * x[c].z + w[c].w * x[c].w;

        #pragma unroll
        for (int off = 32; off > 0; off >>= 1)
            acc += __shfl_xor(acc, off, 64);

        const float y = tanhf(acc + bk);
        const int b = b0 + r;
        if (lane == 0) out_hidden[b * Hn + k] = y;   // store #1 of 7

        float* __restrict__ orow = out_wih + ((size_t)b * Hn + k) * Dn;
        #pragma unroll
        for (int c = 0; c < 6; ++c) {                // stores #2..#7
            const int e = c * 64 + lane;
            const float4 a4 = ((const float4*)lds)[e];
            const float4 b4 = ((const float4*)lds)[384 + e];
            const float4 c4 = ((const float4*)lds)[768 + e];
            const float4 d4 = ((const float4*)lds)[1152 + e];
            nfloat4 o;
            o.x = w[c].x + ALPHA * (y * x[c].x * a4.x + x[c].x * b4.x + y * c4.x + d4.x);
            o.y = w[c].y + ALPHA * (y * x[c].y * a4.y + x[c].y * b4.y + y * c4.y + d4.y);
            o.z = w[c].z + ALPHA * (y * x[c].z * a4.z + x[c].z * b4.z + y * c4.z + d4.z);
            o.w = w[c].w + ALPHA * (y * x[c].w * a4.w + x[c].w * b4.w + y * c4.w + d4.w);
            __builtin_nontemporal_store(o, (nfloat4*)(orow + c * 256 + lane * 4));
        }

        // Pin stores BEFORE the next DMA issue (count integrity), then refill
        // the slot just consumed with row r+2.
        asm volatile("" ::: "memory");
        __builtin_amdgcn_sched_barrier(0);
        if (r + 2 < RPW) dma_row(r + 2, (r & 1) ? slot1 : slot0);
        asm volatile("" ::: "memory");
    }
}

extern "C" void kernel_launch(void* const* d_in, const int* in_sizes, int n_in,
                              void* d_out, int out_size, void* d_ws, size_t ws_size,
                              hipStream_t stream) {
    const float* inputs = (const float*)d_in[0];
    const float* hidden = (const float*)d_in[1];
    const float* wih    = (const float*)d_in[2];
    const float* Wa     = (const float*)d_in[3];
    const float* Wb     = (const float*)d_in[4];
    const float* Wc     = (const float*)d_in[5];
    const float* Wd     = (const float*)d_in[6];
    const float* bih    = (const float*)d_in[7];
    // d_in[8] = W_dop, d_in[9] = b_dop feed only _dopamine (not returned) -> skipped.

    float* out_hidden = (float*)d_out;                    // B*H floats
    float* out_wih    = (float*)d_out + (size_t)Bn * Hn;  // B*H*D floats

    const size_t lds_bytes = (size_t)LDS_FLOATS * sizeof(float);   // 120 KB
    // Opt in to >64 KB dynamic LDS (host-side, idempotent, capture-safe).
    (void)hipFuncSetAttribute((const void*)prnn_fused_kernel,
                              hipFuncAttributeMaxDynamicSharedMemorySize,
                              (int)lds_bytes);

    prnn_fused_kernel<<<dim3(Hn * 2), dim3(256), lds_bytes, stream>>>(
        inputs, hidden, wih, Wa, Wb, Wc, Wd, bih, out_hidden, out_wih);
}

// Round 7
// 164.314 us; speedup vs baseline: 1.2222x; 1.2222x over previous
//
#include <hip/hip_runtime.h>

// Problem constants: B=64, I=512, H=1024, D=I+H=1536
constexpr int Bn = 64;
constexpr int In = 512;
constexpr int Hn = 1024;
constexpr int Dn = 1536;
constexpr float ALPHA = 0.001f;

// Native 4-float vector: supports vector arithmetic + __builtin_nontemporal_store.
typedef float nfloat4 __attribute__((ext_vector_type(4)));

// Block = one k, all 64 b. 1024 blocks x 256 threads (4 waves x 16 rows).
// R7 structure: rows processed in GROUPS OF 4 per wave.
//   [24-instr wih read burst: 24 KB DRAM reads, no writes]
//   [4x: x from L2 (DRAM-neutral, double-buffered) -> dot -> reduce -> tanh
//        -> update from regs+LDS -> 6 KB NT store burst]
// => per-wave DRAM direction runs are 24 KB read / 24 KB write instead of
//    6/6 KB. Theory: R1/R4/R5 flat at ~4.2 TB/s across occupancy 30-64% and
//    pipeline depth 0-2 => bound by DRAM read/write turnaround, not latency.
// W staged to LDS once per block, PRE-SCALED by ALPHA:
//   out = w + y*(x*sA + sC) + (x*sB + sD), sX = ALPHA*WX  (4 VALU ops/elem).
__global__ __launch_bounds__(256) void prnn_fused_kernel(
    const float* __restrict__ inputs,   // B x I
    const float* __restrict__ hidden,   // B x H
    const float* __restrict__ wih,      // B x H x D
    const float* __restrict__ Wa,       // H x D
    const float* __restrict__ Wb,       // H x D
    const float* __restrict__ Wc,       // H x D
    const float* __restrict__ Wd,       // H x D
    const float* __restrict__ bih,      // H
    float* __restrict__ out_hidden,     // B x H
    float* __restrict__ out_wih)        // B x H x D
{
    __shared__ nfloat4 sW[4 * (Dn / 4)];   // 24 KB, alpha-prescaled A,B,C,D

    const int k   = blockIdx.x;
    const int tid = threadIdx.x;

    // Cooperative LDS stage of ALPHA*Wa..Wd row k (384 nfloat4 per tensor).
    {
        const nfloat4* wa4 = (const nfloat4*)(Wa + (size_t)k * Dn);
        const nfloat4* wb4 = (const nfloat4*)(Wb + (size_t)k * Dn);
        const nfloat4* wc4 = (const nfloat4*)(Wc + (size_t)k * Dn);
        const nfloat4* wd4 = (const nfloat4*)(Wd + (size_t)k * Dn);
        #pragma unroll
        for (int e = 0; e < 2; ++e) {
            const int i = tid + e * 256;
            if (i < 384) {
                sW[i]        = wa4[i] * ALPHA;
                sW[384 + i]  = wb4[i] * ALPHA;
                sW[768 + i]  = wc4[i] * ALPHA;
                sW[1152 + i] = wd4[i] * ALPHA;
            }
        }
    }
    __syncthreads();

    const int wave = tid >> 6;
    const int lane = tid & 63;
    const int b0   = wave * 16;           // 16 rows per wave, 4 groups of 4
    const float bk = bih[k];
    const int base = lane * 4;

    nfloat4 w[4][6];      // 4 rows of wih (96 VGPR): the DRAM read burst
    nfloat4 xb[2][6];     // x double-buffer (L2-hot)

    auto load_x = [&](int b, nfloat4 (&x)[6]) {
        const float* __restrict__ xin  = inputs + b * In;
        const float* __restrict__ xhid = hidden + b * Hn;
        #pragma unroll
        for (int c = 0; c < 6; ++c) {
            const int idx = c * 256 + base;
            x[c] = (c < 2) ? *(const nfloat4*)(xin + idx)
                           : *(const nfloat4*)(xhid + (idx - In));
        }
    };

    #pragma unroll
    for (int g = 0; g < 4; ++g) {         // fully unrolled: static indices
        const int bg = b0 + g * 4;

        // ---- 24 KB DRAM read burst: 4 rows of wih ----
        #pragma unroll
        for (int q = 0; q < 4; ++q) {
            const float* __restrict__ wrow =
                wih + ((size_t)(bg + q) * Hn + k) * Dn;
            #pragma unroll
            for (int c = 0; c < 6; ++c)
                w[q][c] = *(const nfloat4*)(wrow + c * 256 + base);
        }
        load_x(bg, xb[0]);

        // ---- per-row compute + 24 KB write phase (no DRAM reads) ----
        #pragma unroll
        for (int q = 0; q < 4; ++q) {
            if (q < 3) load_x(bg + q + 1, xb[(q + 1) & 1]);   // L2 prefetch
            nfloat4 (&x)[6] = xb[q & 1];

            float acc = 0.0f;
            #pragma unroll
            for (int c = 0; c < 6; ++c) {
                nfloat4 p = w[q][c] * x[c];
                acc += (p.x + p.y) + (p.z + p.w);
            }
            #pragma unroll
            for (int off = 32; off > 0; off >>= 1)
                acc += __shfl_xor(acc, off, 64);

            const float y = tanhf(acc + bk);
            const int b = bg + q;
            if (lane == 0) out_hidden[b * Hn + k] = y;

            float* __restrict__ orow = out_wih + ((size_t)b * Hn + k) * Dn;
            #pragma unroll
            for (int c = 0; c < 6; ++c) {
                const int e = c * 64 + lane;
                const nfloat4 m1 = x[c] * sW[e]       + sW[768 + e];   // y-term
                const nfloat4 m2 = x[c] * sW[384 + e] + sW[1152 + e];  // const
                const nfloat4 o  = (w[q][c] + m2) + y * m1;
                __builtin_nontemporal_store(o, (nfloat4*)(orow + c * 256 + base));
            }
        }
    }
}

extern "C" void kernel_launch(void* const* d_in, const int* in_sizes, int n_in,
                              void* d_out, int out_size, void* d_ws, size_t ws_size,
                              hipStream_t stream) {
    const float* inputs = (const float*)d_in[0];
    const float* hidden = (const float*)d_in[1];
    const float* wih    = (const float*)d_in[2];
    const float* Wa     = (const float*)d_in[3];
    const float* Wb     = (const float*)d_in[4];
    const float* Wc     = (const float*)d_in[5];
    const float* Wd     = (const float*)d_in[6];
    const float* bih    = (const float*)d_in[7];
    // d_in[8] = W_dop, d_in[9] = b_dop feed only _dopamine (not returned) -> skipped.

    float* out_hidden = (float*)d_out;                    // B*H floats
    float* out_wih    = (float*)d_out + (size_t)Bn * Hn;  // B*H*D floats

    prnn_fused_kernel<<<dim3(Hn), dim3(256), 0, stream>>>(
        inputs, hidden, wih, Wa, Wb, Wc, Wd, bih, out_hidden, out_wih);
}